// Round 2
// baseline (3652.221 us; speedup 1.0000x reference)
//
#include <hip/hip_runtime.h>
#include <cstdint>
#include <cstddef>

typedef _Float16 h16;
typedef __attribute__((ext_vector_type(8))) _Float16 half8;
typedef __attribute__((ext_vector_type(4))) _Float16 half4;
typedef __attribute__((ext_vector_type(4))) float f32x4;

#define D 1024
#define NTOK 65536
#define BM 128
#define BN 128
#define BK 64
#define KTILES (D / BK)  // 16
#define NLIN 12

// Swizzled element position for activation/weight layout:
// within each row's 128B chunk (64 fp16), 16B granules are XOR-permuted by (row&7).
// Writer and reader use the SAME involution (rule #21: both-sides-or-neither).
__device__ __forceinline__ size_t swz_pos(int t, int o) {
  return (size_t)t * D + ((o >> 6) << 6) + ((((o >> 3) & 7) ^ (t & 7)) << 3) + (o & 7);
}

// ---------- dequant: int32 q * group scales -> fp16 W, swizzled by (o&7) ----------
__global__ __launch_bounds__(256) void k_dequant(const int* __restrict__ q,
                                                 const float* __restrict__ s,
                                                 h16* __restrict__ W) {
  const int row = blockIdx.x;        // l*1024 + o
  const int o = row & (D - 1);
  const int k0 = threadIdx.x * 4;
  const int4 qv = *(const int4*)(q + (size_t)row * D + k0);
  const float sc = s[(size_t)row * (D / 16) + (k0 >> 4)];
  half4 wv;
  wv.x = (h16)((float)qv.x * sc);
  wv.y = (h16)((float)qv.y * sc);
  wv.z = (h16)((float)qv.z * sc);
  wv.w = (h16)((float)qv.w * sc);
  const int chunk = k0 >> 6;
  const int pg = (k0 >> 3) & 7;
  const size_t idx = (size_t)row * D + (chunk << 6) + (((pg ^ (o & 7)) << 3) + (k0 & 7));
  *(half4*)(W + idx) = wv;
}

// ---------- convert: x fp32 -> fp16 swizzled by (t&7) ----------
__global__ __launch_bounds__(256) void k_convert(const float* __restrict__ x, h16* __restrict__ X) {
  const int idx = blockIdx.x * 256 + threadIdx.x;  // global 8-elem granule id
  const int t = idx >> 7, g = idx & 127;
  const int tk = ((g >> 3) << 6) + (((g & 7) ^ (t & 7)) << 3);
  const float* src = x + (size_t)t * D + tk;
  const f32x4 a = *(const f32x4*)(src);
  const f32x4 b = *(const f32x4*)(src + 4);
  half8 v;
  v[0] = (h16)a.x; v[1] = (h16)a.y; v[2] = (h16)a.z; v[3] = (h16)a.w;
  v[4] = (h16)b.x; v[5] = (h16)b.y; v[6] = (h16)b.z; v[7] = (h16)b.w;
  *(half8*)(X + (size_t)t * D + (size_t)g * 8) = v;
}

// ---------- GEMM: out[t,o] = act(sum_k A[t,k]*W[o,k] + bias[o] (+res)) ----------
__global__ __launch_bounds__(256, 2) void k_gemm(const h16* __restrict__ A,
                                                 const h16* __restrict__ W,
                                                 const float* __restrict__ bias,
                                                 const h16* res, h16* out, int relu) {
  __shared__ _Float16 ldsA[2][BM * BK];
  __shared__ _Float16 ldsB[2][BM * BK];

  const int bid = blockIdx.x;
  const int swzb = (bid & 7) * 512 + (bid >> 3);  // bijective: 4096 % 8 == 0
  const int tm = swzb >> 3;                       // 0..511 (M tile)
  const int tn = swzb & 7;                        // 0..7   (N tile)
  const int tid = threadIdx.x;
  const int lane = tid & 63;
  const int w = tid >> 6;
  const int wm = w >> 1, wn = w & 1;

  // ds_read offsets (half units), swizzle-corrected.
  // Fragment: lane&15 = row within 16-block, lane>>4 = k-granule; h = k sub-tile (0..1).
  int aoff[4][2], boff[4][2];
#pragma unroll
  for (int f = 0; f < 4; ++f) {
#pragma unroll
    for (int h = 0; h < 2; ++h) {
      const int ra = wm * 64 + f * 16 + (lane & 15);
      const int pa = (h * 4 + (lane >> 4)) ^ (ra & 7);
      aoff[f][h] = ra * BK + pa * 8;
      const int rb = wn * 64 + f * 16 + (lane & 15);
      const int pb = (h * 4 + (lane >> 4)) ^ (rb & 7);
      boff[f][h] = rb * BK + pb * 8;
    }
  }

  // staging: wave w stages rows [32w,32w+32) of each tile; per-lane GLOBAL addr
  // carries the swizzle, LDS dest linear (global_load_lds constraint).
  const h16* asrc[4];
  const h16* bsrc[4];
#pragma unroll
  for (int it = 0; it < 4; ++it) {
    const int gidx = w * 256 + it * 64 + lane;
    const int row = gidx >> 3, p = gidx & 7;
    asrc[it] = A + (size_t)(tm * BM + row) * D + p * 8;
    bsrc[it] = W + (size_t)(tn * BN + row) * D + p * 8;
  }

  f32x4 acc[4][4];
#pragma unroll
  for (int i = 0; i < 4; ++i)
#pragma unroll
    for (int j = 0; j < 4; ++j) acc[i][j] = (f32x4)0.f;

  auto stage = [&](int buf, int kt) {
    _Float16* la = &ldsA[buf][w * 2048];
    _Float16* lb = &ldsB[buf][w * 2048];
#pragma unroll
    for (int it = 0; it < 4; ++it) {
      __builtin_amdgcn_global_load_lds(
          (const __attribute__((address_space(1))) void*)(asrc[it] + (size_t)kt * BK),
          (__attribute__((address_space(3))) void*)(la + it * 512), 16, 0, 0);
      __builtin_amdgcn_global_load_lds(
          (const __attribute__((address_space(1))) void*)(bsrc[it] + (size_t)kt * BK),
          (__attribute__((address_space(3))) void*)(lb + it * 512), 16, 0, 0);
    }
  };

  stage(0, 0);
  asm volatile("s_waitcnt vmcnt(0)" ::: "memory");
  __syncthreads();

  for (int kt = 0; kt < KTILES; ++kt) {
    const int buf = kt & 1;
    if (kt + 1 < KTILES) stage(buf ^ 1, kt + 1);

    half8 af[4][2], bf[4][2];
#pragma unroll
    for (int f = 0; f < 4; ++f) {
#pragma unroll
      for (int h = 0; h < 2; ++h) {
        af[f][h] = *(const half8*)(&ldsA[buf][aoff[f][h]]);
        bf[f][h] = *(const half8*)(&ldsB[buf][boff[f][h]]);
      }
    }
#pragma unroll
    for (int h = 0; h < 2; ++h)
#pragma unroll
      for (int mf = 0; mf < 4; ++mf)
#pragma unroll
        for (int nf = 0; nf < 4; ++nf)
          acc[mf][nf] = __builtin_amdgcn_mfma_f32_16x16x32_f16(af[mf][h], bf[nf][h], acc[mf][nf], 0, 0, 0);

    __syncthreads();  // compiler emits vmcnt+lgkmcnt drain here: next buf is ready
  }

  // epilogue: bias (+res) (+relu), write fp16 swizzled (C/D map: col=lane&15, row=(lane>>4)*4+j)
#pragma unroll
  for (int nf = 0; nf < 4; ++nf) {
    const int o = tn * BN + wn * 64 + nf * 16 + (lane & 15);
    const float bv = bias[o];
#pragma unroll
    for (int mf = 0; mf < 4; ++mf) {
      const int m0 = tm * BM + wm * 64 + mf * 16 + ((lane >> 4) << 2);
#pragma unroll
      for (int j = 0; j < 4; ++j) {
        const int t = m0 + j;
        float v = acc[mf][nf][j] + bv;
        if (res) v += (float)res[swz_pos(t, o)];
        if (relu) v = fmaxf(v, 0.f);
        out[swz_pos(t, o)] = (h16)v;
      }
    }
  }
}

// ---------- LayerNorm, wave per row (1024 elems = 16/lane) ----------
__device__ __forceinline__ void ln_stats(const half8& v0, const half8& v1, float& mu, float& rs) {
  float sum = 0.f, ss = 0.f;
#pragma unroll
  for (int j = 0; j < 8; ++j) {
    float f0 = (float)v0[j], f1 = (float)v1[j];
    sum += f0 + f1;
    ss += f0 * f0 + f1 * f1;
  }
#pragma unroll
  for (int m = 32; m > 0; m >>= 1) {
    sum += __shfl_xor(sum, m);
    ss += __shfl_xor(ss, m);
  }
  mu = sum * (1.f / D);
  const float var = ss * (1.f / D) - mu * mu;
  rs = rsqrtf(var + 1e-5f);
}

__global__ __launch_bounds__(256) void k_ln_mid(h16* h, const float* __restrict__ w, const float* __restrict__ b) {
  const int t = blockIdx.x * 4 + (threadIdx.x >> 6);
  const int lane = threadIdx.x & 63;
  h16* row = h + (size_t)t * D;
  half8 v0 = *(const half8*)(row + (size_t)lane * 8);
  half8 v1 = *(const half8*)(row + (size_t)(lane + 64) * 8);
  float mu, rs;
  ln_stats(v0, v1, mu, rs);
  const int tk0 = ((lane >> 3) << 6) + (((lane & 7) ^ (t & 7)) << 3);
  const int g1 = lane + 64;
  const int tk1 = ((g1 >> 3) << 6) + (((g1 & 7) ^ (t & 7)) << 3);
#pragma unroll
  for (int j = 0; j < 8; ++j) {
    v0[j] = (h16)(((float)v0[j] - mu) * rs * w[tk0 + j] + b[tk0 + j]);
    v1[j] = (h16)(((float)v1[j] - mu) * rs * w[tk1 + j] + b[tk1 + j]);
  }
  *(half8*)(row + (size_t)lane * 8) = v0;
  *(half8*)(row + (size_t)(lane + 64) * 8) = v1;
}

__global__ __launch_bounds__(256) void k_ln_final(const h16* __restrict__ h, const float* __restrict__ w,
                                                  const float* __restrict__ b, float* __restrict__ out) {
  const int t = blockIdx.x * 4 + (threadIdx.x >> 6);
  const int lane = threadIdx.x & 63;
  const h16* row = h + (size_t)t * D;
  half8 v0 = *(const half8*)(row + (size_t)lane * 8);
  half8 v1 = *(const half8*)(row + (size_t)(lane + 64) * 8);
  float mu, rs;
  ln_stats(v0, v1, mu, rs);
  const int tk0 = ((lane >> 3) << 6) + (((lane & 7) ^ (t & 7)) << 3);
  const int g1 = lane + 64;
  const int tk1 = ((g1 >> 3) << 6) + (((g1 & 7) ^ (t & 7)) << 3);
  float* orow = out + (size_t)t * D;
#pragma unroll
  for (int j = 0; j < 8; ++j) {
    orow[tk0 + j] = ((float)v0[j] - mu) * rs * w[tk0 + j] + b[tk0 + j];
    orow[tk1 + j] = ((float)v1[j] - mu) * rs * w[tk1 + j] + b[tk1 + j];
  }
}

extern "C" void kernel_launch(void* const* d_in, const int* in_sizes, int n_in,
                              void* d_out, int out_size, void* d_ws, size_t ws_size,
                              hipStream_t stream) {
  const float* x = (const float*)d_in[0];
  const int* qw = (const int*)d_in[1];
  const float* scales = (const float*)d_in[2];
  const float* bias = (const float*)d_in[3];
  const float* lnw = (const float*)d_in[4];
  const float* lnb = (const float*)d_in[5];
  float* out = (float*)d_out;

  // Exact scratch need: X (65536x1024 fp16 = 128MB) + W (12x1024x1024 fp16 = 24MB)
  if (ws_size < (size_t)152 * 1024 * 1024) return;

  char* ws = (char*)d_ws;
  h16* X = (h16*)ws;                                    // 128MB activation + residual
  h16* W = (h16*)(ws + (size_t)128 * 1024 * 1024);      // 12 x 2MB fp16, swizzled
  h16* Y = (h16*)d_out;                                 // scratch in d_out (dead before final LN)
  h16* Z = Y + (size_t)64 * 1024 * 1024;                // second half of d_out

  k_dequant<<<NLIN * D, 256, 0, stream>>>(qw, scales, W);
  k_convert<<<(NTOK * (D / 8)) / 256, 256, 0, stream>>>(x, X);

  const int GG = (NTOK / BM) * (D / BN);  // 4096
  for (int blk = 0; blk < 4; ++blk) {
    const int l0 = 3 * blk;
    k_gemm<<<GG, 256, 0, stream>>>(X, W + (size_t)(l0 + 0) * D * D, bias + (l0 + 0) * D, nullptr, Y, 1);
    k_gemm<<<GG, 256, 0, stream>>>(Y, W + (size_t)(l0 + 1) * D * D, bias + (l0 + 1) * D, nullptr, Z, 1);
    k_gemm<<<GG, 256, 0, stream>>>(Z, W + (size_t)(l0 + 2) * D * D, bias + (l0 + 2) * D, X, X, 0);
    if (blk < 3)
      k_ln_mid<<<NTOK / 4, 256, 0, stream>>>(X, lnw + blk * D, lnb + blk * D);
    else
      k_ln_final<<<NTOK / 4, 256, 0, stream>>>(X, lnw + blk * D, lnb + blk * D, out);
  }
}

// Round 3
// 2443.880 us; speedup vs baseline: 1.4944x; 1.4944x over previous
//
#include <hip/hip_runtime.h>
#include <cstdint>
#include <cstddef>

typedef _Float16 h16;
typedef __attribute__((ext_vector_type(8))) _Float16 half8;
typedef __attribute__((ext_vector_type(4))) _Float16 half4;
typedef __attribute__((ext_vector_type(4))) float f32x4;

#define D 1024
#define NTOK 65536
#define BM 128
#define BN 128
#define BK 64
#define KTILES (D / BK)  // 16
#define NLIN 12

// Swizzled element position for activation/weight layout:
// within each row's 128B chunk (64 fp16), 16B granules are XOR-permuted by (row&7).
__device__ __forceinline__ size_t swz_pos(int t, int o) {
  return (size_t)t * D + ((o >> 6) << 6) + ((((o >> 3) & 7) ^ (t & 7)) << 3) + (o & 7);
}

// ---------- dequant: int32 q * group scales -> fp16 W, swizzled by (o&7) ----------
__global__ __launch_bounds__(256) void k_dequant(const int* __restrict__ q,
                                                 const float* __restrict__ s,
                                                 h16* __restrict__ W) {
  const int row = blockIdx.x;        // l*1024 + o
  const int o = row & (D - 1);
  const int k0 = threadIdx.x * 4;
  const int4 qv = *(const int4*)(q + (size_t)row * D + k0);
  const float sc = s[(size_t)row * (D / 16) + (k0 >> 4)];
  half4 wv;
  wv.x = (h16)((float)qv.x * sc);
  wv.y = (h16)((float)qv.y * sc);
  wv.z = (h16)((float)qv.z * sc);
  wv.w = (h16)((float)qv.w * sc);
  const int chunk = k0 >> 6;
  const int pg = (k0 >> 3) & 7;
  const size_t idx = (size_t)row * D + (chunk << 6) + (((pg ^ (o & 7)) << 3) + (k0 & 7));
  *(half4*)(W + idx) = wv;
}

// ---------- convert: x fp32 -> fp16 swizzled by (t&7) ----------
__global__ __launch_bounds__(256) void k_convert(const float* __restrict__ x, h16* __restrict__ X) {
  const int idx = blockIdx.x * 256 + threadIdx.x;  // global 8-elem granule id
  const int t = idx >> 7, g = idx & 127;
  const int tk = ((g >> 3) << 6) + (((g & 7) ^ (t & 7)) << 3);
  const float* src = x + (size_t)t * D + tk;
  const f32x4 a = *(const f32x4*)(src);
  const f32x4 b = *(const f32x4*)(src + 4);
  half8 v;
  v[0] = (h16)a.x; v[1] = (h16)a.y; v[2] = (h16)a.z; v[3] = (h16)a.w;
  v[4] = (h16)b.x; v[5] = (h16)b.y; v[6] = (h16)b.z; v[7] = (h16)b.w;
  *(half8*)(X + (size_t)t * D + (size_t)g * 8) = v;
}

// ---------- GEMM: out[t,o] = act(sum_k A[t,k]*W[o,k] + bias[o] (+res)) ----------
// Single-buffer LDS (32KB) -> 4 blocks/CU; LDS-transpose coalesced epilogue.
__global__ __launch_bounds__(256, 4) void k_gemm(const h16* __restrict__ A,
                                                 const h16* __restrict__ W,
                                                 const float* __restrict__ bias,
                                                 const h16* res, h16* out, int relu) {
  __shared__ _Float16 lds_s[BM * BK * 2];  // A tile [0,8192), B tile [8192,16384); C reuse all 32KB
  _Float16* ldsA = lds_s;
  _Float16* ldsB = lds_s + BM * BK;

  const int bid = blockIdx.x;
  const int swzb = (bid & 7) * 512 + (bid >> 3);  // bijective: 4096 % 8 == 0
  const int tm = swzb >> 3;                       // 0..511 (M tile)
  const int tn = swzb & 7;                        // 0..7   (N tile)
  const int tid = threadIdx.x;
  const int lane = tid & 63;
  const int w = tid >> 6;
  const int wm = w >> 1, wn = w & 1;

  // ds_read offsets (half units), swizzle-corrected.
  int aoff[4][2], boff[4][2];
#pragma unroll
  for (int f = 0; f < 4; ++f) {
#pragma unroll
    for (int h = 0; h < 2; ++h) {
      const int ra = wm * 64 + f * 16 + (lane & 15);
      const int pa = (h * 4 + (lane >> 4)) ^ (ra & 7);
      aoff[f][h] = ra * BK + pa * 8;
      const int rb = wn * 64 + f * 16 + (lane & 15);
      const int pb = (h * 4 + (lane >> 4)) ^ (rb & 7);
      boff[f][h] = rb * BK + pb * 8;
    }
  }

  // staging: wave w stages rows [32w,32w+32) of each tile; per-lane GLOBAL addr
  // carries the swizzle, LDS dest linear (global_load_lds constraint).
  const h16* asrc[4];
  const h16* bsrc[4];
#pragma unroll
  for (int it = 0; it < 4; ++it) {
    const int gidx = w * 256 + it * 64 + lane;
    const int row = gidx >> 3, p = gidx & 7;
    asrc[it] = A + (size_t)(tm * BM + row) * D + p * 8;
    bsrc[it] = W + (size_t)(tn * BN + row) * D + p * 8;
  }

  f32x4 acc[4][4];
#pragma unroll
  for (int i = 0; i < 4; ++i)
#pragma unroll
    for (int j = 0; j < 4; ++j) acc[i][j] = (f32x4)0.f;

  for (int kt = 0; kt < KTILES; ++kt) {
    // stage current K-tile
    {
      _Float16* la = ldsA + w * 2048;
      _Float16* lb = ldsB + w * 2048;
#pragma unroll
      for (int it = 0; it < 4; ++it) {
        __builtin_amdgcn_global_load_lds(
            (const __attribute__((address_space(1))) void*)(asrc[it] + (size_t)kt * BK),
            (__attribute__((address_space(3))) void*)(la + it * 512), 16, 0, 0);
        __builtin_amdgcn_global_load_lds(
            (const __attribute__((address_space(1))) void*)(bsrc[it] + (size_t)kt * BK),
            (__attribute__((address_space(3))) void*)(lb + it * 512), 16, 0, 0);
      }
    }
    __syncthreads();  // vmcnt drain: LDS tile ready

    half8 af[4][2], bf[4][2];
#pragma unroll
    for (int f = 0; f < 4; ++f) {
#pragma unroll
      for (int h = 0; h < 2; ++h) {
        af[f][h] = *(const half8*)(&ldsA[aoff[f][h]]);
        bf[f][h] = *(const half8*)(&ldsB[boff[f][h]]);
      }
    }
#pragma unroll
    for (int h = 0; h < 2; ++h)
#pragma unroll
      for (int mf = 0; mf < 4; ++mf)
#pragma unroll
        for (int nf = 0; nf < 4; ++nf)
          acc[mf][nf] = __builtin_amdgcn_mfma_f32_16x16x32_f16(af[mf][h], bf[nf][h], acc[mf][nf], 0, 0, 0);

    __syncthreads();  // all reads done before next stage overwrites
  }

  // ---- epilogue phase 1: acc (+bias, +relu) -> LDS in output-swizzled layout ----
  // C/D map: col(o) = lane&15, row(t) = (lane>>4)*4 + j
  _Float16* ldc = lds_s;  // 128x128 fp16 = 32KB, exactly the staging LDS
#pragma unroll
  for (int nf = 0; nf < 4; ++nf) {
    const int ol = wn * 64 + nf * 16 + (lane & 15);
    const float bv = bias[tn * BN + ol];
#pragma unroll
    for (int mf = 0; mf < 4; ++mf) {
      const int tl0 = wm * 64 + mf * 16 + ((lane >> 4) << 2);
#pragma unroll
      for (int j = 0; j < 4; ++j) {
        const int tl = tl0 + j;
        float v = acc[mf][nf][j] + bv;
        if (relu) v = fmaxf(v, 0.f);
        // local swizzle == global swizzle: (tm*128+tl)&7 == tl&7, chunk/granule local
        ldc[tl * 128 + ((ol >> 6) << 6) + ((((ol >> 3) & 7) ^ (tl & 7)) << 3) + (ol & 7)] = (h16)v;
      }
    }
  }
  __syncthreads();

  // ---- epilogue phase 2: coalesced half8 read-back (+res), full-line global stores ----
#pragma unroll
  for (int p = 0; p < 8; ++p) {
    const int g = p * 256 + tid;
    const int tl = g >> 4, c = g & 15;
    half8 v = *(const half8*)(ldc + tl * 128 + c * 8);
    const size_t gpos = (size_t)(tm * BM + tl) * D + tn * BN + c * 8;
    if (res) {
      const half8 r = *(const half8*)(res + gpos);
#pragma unroll
      for (int j = 0; j < 8; ++j) v[j] = (h16)((float)v[j] + (float)r[j]);
    }
    *(half8*)(out + gpos) = v;
  }
}

// ---------- LayerNorm, wave per row (1024 elems = 16/lane) ----------
__device__ __forceinline__ void ln_stats(const half8& v0, const half8& v1, float& mu, float& rs) {
  float sum = 0.f, ss = 0.f;
#pragma unroll
  for (int j = 0; j < 8; ++j) {
    float f0 = (float)v0[j], f1 = (float)v1[j];
    sum += f0 + f1;
    ss += f0 * f0 + f1 * f1;
  }
#pragma unroll
  for (int m = 32; m > 0; m >>= 1) {
    sum += __shfl_xor(sum, m);
    ss += __shfl_xor(ss, m);
  }
  mu = sum * (1.f / D);
  const float var = ss * (1.f / D) - mu * mu;
  rs = rsqrtf(var + 1e-5f);
}

__global__ __launch_bounds__(256) void k_ln_mid(h16* h, const float* __restrict__ w, const float* __restrict__ b) {
  const int t = blockIdx.x * 4 + (threadIdx.x >> 6);
  const int lane = threadIdx.x & 63;
  h16* row = h + (size_t)t * D;
  half8 v0 = *(const half8*)(row + (size_t)lane * 8);
  half8 v1 = *(const half8*)(row + (size_t)(lane + 64) * 8);
  float mu, rs;
  ln_stats(v0, v1, mu, rs);
  const int tk0 = ((lane >> 3) << 6) + (((lane & 7) ^ (t & 7)) << 3);
  const int g1 = lane + 64;
  const int tk1 = ((g1 >> 3) << 6) + (((g1 & 7) ^ (t & 7)) << 3);
#pragma unroll
  for (int j = 0; j < 8; ++j) {
    v0[j] = (h16)(((float)v0[j] - mu) * rs * w[tk0 + j] + b[tk0 + j]);
    v1[j] = (h16)(((float)v1[j] - mu) * rs * w[tk1 + j] + b[tk1 + j]);
  }
  *(half8*)(row + (size_t)lane * 8) = v0;
  *(half8*)(row + (size_t)(lane + 64) * 8) = v1;
}

__global__ __launch_bounds__(256) void k_ln_final(const h16* __restrict__ h, const float* __restrict__ w,
                                                  const float* __restrict__ b, float* __restrict__ out) {
  const int t = blockIdx.x * 4 + (threadIdx.x >> 6);
  const int lane = threadIdx.x & 63;
  const h16* row = h + (size_t)t * D;
  half8 v0 = *(const half8*)(row + (size_t)lane * 8);
  half8 v1 = *(const half8*)(row + (size_t)(lane + 64) * 8);
  float mu, rs;
  ln_stats(v0, v1, mu, rs);
  const int tk0 = ((lane >> 3) << 6) + (((lane & 7) ^ (t & 7)) << 3);
  const int g1 = lane + 64;
  const int tk1 = ((g1 >> 3) << 6) + (((g1 & 7) ^ (t & 7)) << 3);
  float* orow = out + (size_t)t * D;
#pragma unroll
  for (int j = 0; j < 8; ++j) {
    orow[tk0 + j] = ((float)v0[j] - mu) * rs * w[tk0 + j] + b[tk0 + j];
    orow[tk1 + j] = ((float)v1[j] - mu) * rs * w[tk1 + j] + b[tk1 + j];
  }
}

extern "C" void kernel_launch(void* const* d_in, const int* in_sizes, int n_in,
                              void* d_out, int out_size, void* d_ws, size_t ws_size,
                              hipStream_t stream) {
  const float* x = (const float*)d_in[0];
  const int* qw = (const int*)d_in[1];
  const float* scales = (const float*)d_in[2];
  const float* bias = (const float*)d_in[3];
  const float* lnw = (const float*)d_in[4];
  const float* lnb = (const float*)d_in[5];
  float* out = (float*)d_out;

  // Exact scratch need: X (65536x1024 fp16 = 128MB) + W (12x1024x1024 fp16 = 24MB)
  if (ws_size < (size_t)152 * 1024 * 1024) return;

  char* ws = (char*)d_ws;
  h16* X = (h16*)ws;                                    // 128MB activation + residual
  h16* W = (h16*)(ws + (size_t)128 * 1024 * 1024);      // 12 x 2MB fp16, swizzled
  h16* Y = (h16*)d_out;                                 // scratch in d_out (dead before final LN)
  h16* Z = Y + (size_t)64 * 1024 * 1024;                // second half of d_out

  k_dequant<<<NLIN * D, 256, 0, stream>>>(qw, scales, W);
  k_convert<<<(NTOK * (D / 8)) / 256, 256, 0, stream>>>(x, X);

  const int GG = (NTOK / BM) * (D / BN);  // 4096
  for (int blk = 0; blk < 4; ++blk) {
    const int l0 = 3 * blk;
    k_gemm<<<GG, 256, 0, stream>>>(X, W + (size_t)(l0 + 0) * D * D, bias + (l0 + 0) * D, nullptr, Y, 1);
    k_gemm<<<GG, 256, 0, stream>>>(Y, W + (size_t)(l0 + 1) * D * D, bias + (l0 + 1) * D, nullptr, Z, 1);
    k_gemm<<<GG, 256, 0, stream>>>(Z, W + (size_t)(l0 + 2) * D * D, bias + (l0 + 2) * D, X, X, 0);
    if (blk < 3)
      k_ln_mid<<<NTOK / 4, 256, 0, stream>>>(X, lnw + blk * D, lnb + blk * D);
    else
      k_ln_final<<<NTOK / 4, 256, 0, stream>>>(X, lnw + blk * D, lnb + blk * D, out);
  }
}